// Round 1
// 579.045 us; speedup vs baseline: 1.2471x; 1.2471x over previous
//
#include <hip/hip_runtime.h>
#include <hip/hip_bf16.h>
#include <math.h>

#define N_Q 2048
#define K_E 32
#define D_F 128
#define H_N 8
#define DH_N 16
#define EPS_F 1e-5f
#define NEGMAX -3.4028235e38f
#define EPB 8      // edges per E1 block

// R12: single-pass edge pipeline. All 8 edges concurrent, 2 edges register-
// tiled per thread (halves weight loads + addressing per FMA). Thread-local
// LDS round-trips (pp/kv4/agv-gate/qq/sh_es) eliminated -> registers/global.
// LDS 57856 -> 53504 B => 3 blocks/CU. ch head-channels physically rotated by
// 2h: conflict-free B3/B6 writes AND wave-uniform weight indices in B2/B4/B7.

// ---------------------------------------------------------------------------
// Kernel A+B: query LN+Wq (blocks [0,N)) / key Wk (blocks [N,2N)).
// Outputs packed float4: .xyz = vector part, .w = scalar part.
// ---------------------------------------------------------------------------
__global__ __launch_bounds__(128) void k_qk(
    const float* __restrict__ qs_in, const float* __restrict__ qv_in,
    const float* __restrict__ ks_in, const float* __restrict__ kv_in,
    const float* __restrict__ Wq_s, const float* __restrict__ Wq_v, const float* __restrict__ bq,
    const float* __restrict__ Wk_s, const float* __restrict__ Wk_v, const float* __restrict__ bk,
    const float* __restrict__ ln_gs, const float* __restrict__ ln_bs, const float* __restrict__ ln_gv,
    float4* __restrict__ q4, float4* __restrict__ k4,
    float* __restrict__ skip_s, float* __restrict__ skip_v)
{
    const int t = threadIdx.x;
    __shared__ float s[D_F], v[D_F*3], sl[D_F], vl[D_F*3];
    if (blockIdx.x < N_Q) {
        const int n = blockIdx.x;
        s[t] = qs_in[n*D_F + t];
        #pragma unroll
        for (int x = 0; x < 3; ++x) v[t*3+x] = qv_in[(n*D_F + t)*3 + x];
        __syncthreads();
        float mu = 0.f;
        for (int i = 0; i < D_F; ++i) mu += s[i];
        mu *= (1.f/D_F);
        float var = 0.f;
        for (int i = 0; i < D_F; ++i) { float d = s[i]-mu; var += d*d; }
        var *= (1.f/D_F);
        float rstd = rsqrtf(var + EPS_F);
        float ssq = 0.f;
        for (int i = 0; i < D_F*3; ++i) ssq += v[i]*v[i];
        float rrms = rsqrtf(ssq*(1.f/D_F) + EPS_F);
        float a = (s[t]-mu)*rstd*ln_gs[t] + ln_bs[t];
        sl[t] = a; skip_s[n*D_F + t] = a;
        float gv = ln_gv[t];
        #pragma unroll
        for (int x = 0; x < 3; ++x) {
            float b = v[t*3+x]*rrms*gv;
            vl[t*3+x] = b; skip_v[(n*D_F + t)*3 + x] = b;
        }
        __syncthreads();
        float acc = bq[t], a0 = 0.f, a1 = 0.f, a2 = 0.f;
        #pragma unroll 4
        for (int i = 0; i < D_F; ++i) {
            float ws = Wq_s[i*D_F + t]; acc += sl[i]*ws;
            float wv = Wq_v[i*D_F + t];
            a0 += vl[i*3+0]*wv; a1 += vl[i*3+1]*wv; a2 += vl[i*3+2]*wv;
        }
        q4[n*D_F + t] = make_float4(a0, a1, a2, acc);
    } else {
        const int n = blockIdx.x - N_Q;
        s[t] = ks_in[n*D_F + t];
        #pragma unroll
        for (int x = 0; x < 3; ++x) v[t*3+x] = kv_in[(n*D_F + t)*3 + x];
        __syncthreads();
        float acc = bk[t], a0 = 0.f, a1 = 0.f, a2 = 0.f;
        #pragma unroll 4
        for (int i = 0; i < D_F; ++i) {
            float ws = Wk_s[i*D_F + t]; acc += s[i]*ws;
            float wv = Wk_v[i*D_F + t];
            a0 += v[i*3+0]*wv; a1 += v[i*3+1]*wv; a2 += v[i*3+2]*wv;
        }
        k4[n*D_F + t] = make_float4(a0, a1, a2, acc);
    }
}

// ---------------------------------------------------------------------------
// E1: single-pass edge pipeline, 8 edges / block, 2 edges per thread.
// ch channel layout per edge: head h, logical channel j in [0,32) stored at
// physical h*32 + ((j + 2h) & 31)  -> conflict-free writes AND reads; read
// loops index weights by logical (wave-uniform) i.
// ---------------------------------------------------------------------------
__global__ __launch_bounds__(512, 6) void k_edge_bulk(
    const float4* __restrict__ q4, const float4* __restrict__ k4,
    const float* __restrict__ eis, const float* __restrict__ eiv,
    const float* __restrict__ eemb,
    const int* __restrict__ mask, const int* __restrict__ knn,
    const float* __restrict__ Wqk_s, const float* __restrict__ Wqk_v, const float* __restrict__ bqk,
    const float* __restrict__ Wdtp, const float* __restrict__ bdtp,
    const float* __restrict__ Wagv_s, const float* __restrict__ bagv, const float* __restrict__ Wagv_v,
    const float* __restrict__ Wattn, const float* __restrict__ lna_g, const float* __restrict__ lna_b,
    const float* __restrict__ Wval_s, const float* __restrict__ Wval_v, const float* __restrict__ bval,
    float4* __restrict__ ebuf4, float* __restrict__ attn_raw)
{
    const int t = threadIdx.x;
    const int e0 = blockIdx.x * EPB;
    const int n  = e0 >> 5;
    const int k0 = e0 & 31;
    const int s = t >> 7, c = t & 127, h = (t >> 4) & 7, o = t & 15;
    const int rot2 = h * 2;

    __shared__ float4 ch[EPB*256];     // 32 KB (stage-A ee aliased here)
    __shared__ float4 w4[EPB*128];     // 16 KB: (w0,w1,w2,w3) per channel per edge
    __shared__ float  afeat[EPB*8*17]; // 4.25 KB: attn_feat, padded stride 17

    // stage A: ee load (transposed, aliased into ch) + w GEMM into w4
    {
        float* ee = (float*)ch;        // [128][8] floats = 4 KB
        { int idx = t;       int m = idx & 7, i = idx >> 3; ee[i*EPB+m] = eemb[(size_t)(e0+m)*D_F + i]; }
        { int idx = t + 512; int m = idx & 7, i = idx >> 3; ee[i*EPB+m] = eemb[(size_t)(e0+m)*D_F + i]; }
        __syncthreads();
        float acc[EPB];
        float b = bdtp[t];
        #pragma unroll
        for (int m = 0; m < EPB; ++m) acc[m] = b;
        #pragma unroll 2
        for (int i = 0; i < D_F; ++i) {
            float wv = Wdtp[i*512 + t];
            #pragma unroll
            for (int m = 0; m < EPB; ++m) acc[m] += ee[i*EPB+m]*wv;
        }
        __syncthreads();               // all ee reads done -> ch reusable
        float* w4f = (float*)w4;
        const int chn = t & 127, sel = t >> 7;
        #pragma unroll
        for (int m = 0; m < EPB; ++m)
            w4f[(m*128 + chn)*4 + sel] = acc[m];
    }

    const int mA = s, mB = s + 4;
    const int eA = e0 + mA, eB = e0 + mB;

    // per-thread persistent edge irreps (broadcast loads, L1/L2-resident)
    const float esA = eis[eA], esB = eis[eB];
    const float evAx = eiv[eA*3+0], evAy = eiv[eA*3+1], evAz = eiv[eA*3+2];
    const float evBx = eiv[eB*3+0], evBy = eiv[eB*3+1], evBz = eiv[eB*3+2];

    // B1: dtp1 straight from global (no kv/q staging)
    {
        float4 q  = q4[(size_t)n*D_F + c];
        float4 kA = k4[(size_t)knn[eA]*D_F + c];
        float4 kB = k4[(size_t)knn[eB]*D_F + c];
        const int hp = c >> 5, jc = c & 31;
        const int pos0 = hp*32 + ((jc + 2*hp) & 31);             // channel c
        const int pos1 = (hp+4)*32 + ((jc + 2*(hp+4)) & 31);     // channel 128+c
        ch[mA*256 + pos0] = make_float4(q.w*kA.x, q.w*kA.y, q.w*kA.z, q.w*kA.w);
        ch[mA*256 + pos1] = make_float4(kA.w*q.x, kA.w*q.y, kA.w*q.z,
                                        q.x*kA.x + q.y*kA.y + q.z*kA.z);
        ch[mB*256 + pos0] = make_float4(q.w*kB.x, q.w*kB.y, q.w*kB.z, q.w*kB.w);
        ch[mB*256 + pos1] = make_float4(kB.w*q.x, kB.w*q.y, kB.w*q.z,
                                        q.x*kB.x + q.y*kB.y + q.z*kB.z);
    }
    __syncthreads();

    const int chA = mA*256 + h*32, chB = mB*256 + h*32;

    // B2: Wqk — 2 edges per weight load, accumulators in registers
    float pAs, pA0, pA1, pA2, pBs, pB0, pB1, pB2;
    {
        const float bqk_r = bqk[o];
        pAs = bqk_r; pA0 = 0.f; pA1 = 0.f; pA2 = 0.f;
        pBs = bqk_r; pB0 = 0.f; pB1 = 0.f; pB2 = 0.f;
        #pragma unroll 4
        for (int i = 0; i < 32; ++i) {
            int ph = (i + rot2) & 31;
            float4 cA = ch[chA + ph];
            float4 cB = ch[chB + ph];
            float ws = Wqk_s[i*16 + o];
            float wv = Wqk_v[i*16 + o];
            pAs += cA.w*ws; pA0 += cA.x*wv; pA1 += cA.y*wv; pA2 += cA.z*wv;
            pBs += cB.w*ws; pB0 += cB.x*wv; pB1 += cB.y*wv; pB2 += cB.z*wv;
        }
    }
    __syncthreads();

    const int posA = h*32 + ((o + rot2) & 31);        // logical o
    const int posB = h*32 + ((o + 16 + rot2) & 31);   // logical 16+o

    // B3: dtp2 (weighted) — pv in registers, w from w4
    {
        float4 wA = w4[mA*128 + c];
        float4 wB = w4[mB*128 + c];
        ch[mA*256 + posA] = make_float4(pAs*evAx*wA.z, pAs*evAy*wA.z, pAs*evAz*wA.z, pAs*esA*wA.x);
        float dA = pA0*evAx + pA1*evAy + pA2*evAz;
        ch[mA*256 + posB] = make_float4(esA*pA0*wA.w, esA*pA1*wA.w, esA*pA2*wA.w, dA*wA.y);
        ch[mB*256 + posA] = make_float4(pBs*evBx*wB.z, pBs*evBy*wB.z, pBs*evBz*wB.z, pBs*esB*wB.x);
        float dB = pB0*evBx + pB1*evBy + pB2*evBz;
        ch[mB*256 + posB] = make_float4(esB*pB0*wB.w, esB*pB1*wB.w, esB*pB2*wB.w, dB*wB.y);
    }
    __syncthreads();

    // B4: Wagv — 2 edges per weight fetch; gate/vals/vv stay in registers
    float gtA, vlA, vA0, vA1, vA2, gtB, vlB, vB0, vB1, vB2;
    {
        const float bag0 = bagv[h*48 + o];
        const float bag1 = bagv[h*48 + 16 + o];
        const float bag2 = bagv[h*48 + 32 + o];
        float atA = bag0, atB = bag0;
        gtA = bag1; vlA = bag2; vA0 = 0.f; vA1 = 0.f; vA2 = 0.f;
        gtB = bag1; vlB = bag2; vB0 = 0.f; vB1 = 0.f; vB2 = 0.f;
        #pragma unroll 4
        for (int i = 0; i < 32; ++i) {
            int ph = (i + rot2) & 31;
            float4 cA = ch[chA + ph];
            float4 cB = ch[chB + ph];
            const float* wrow = &Wagv_s[(h*32+i)*48];
            float w0 = wrow[o], w1 = wrow[16+o], w2 = wrow[32+o];
            float wv = Wagv_v[(h*32+i)*16 + o];
            atA += cA.w*w0; gtA += cA.w*w1; vlA += cA.w*w2;
            vA0 += cA.x*wv; vA1 += cA.y*wv; vA2 += cA.z*wv;
            atB += cB.w*w0; gtB += cB.w*w1; vlB += cB.w*w2;
            vB0 += cB.x*wv; vB1 += cB.y*wv; vB2 += cB.z*wv;
        }
        afeat[(mA*8 + h)*17 + o] = atA;
        afeat[(mB*8 + h)*17 + o] = atB;
    }
    __syncthreads();

    // B5: logits (t<64: 8 edges x 8 heads) + register-only gating (all threads)
    if (t < EPB*H_N) {
        int m2 = t >> 3, h2 = t & 7;
        const float* af = &afeat[(m2*8 + h2)*17];
        float mu = 0.f;
        #pragma unroll 4
        for (int d2 = 0; d2 < DH_N; ++d2) mu += af[d2];
        mu *= (1.f/DH_N);
        float var = 0.f;
        #pragma unroll 4
        for (int d2 = 0; d2 < DH_N; ++d2) { float dd = af[d2]-mu; var += dd*dd; }
        var *= (1.f/DH_N);
        float rstd = rsqrtf(var + EPS_F);
        float logit = 0.f;
        #pragma unroll 4
        for (int d2 = 0; d2 < DH_N; ++d2) {
            float xn = (af[d2]-mu)*rstd*lna_g[d2] + lna_b[d2];
            logit += xn*Wattn[d2];
        }
        int e2 = e0 + m2;
        if (mask[e2] == 0) logit = NEGMAX;
        attn_raw[h2*(N_Q*K_E) + n*K_E + (k0 + m2)] = logit;
    }
    float sactA = vlA / (1.f + expf(-vlA));
    float gA = 1.f / (1.f + expf(-gtA));
    float qA0 = vA0*gA, qA1 = vA1*gA, qA2 = vA2*gA;
    float sactB = vlB / (1.f + expf(-vlB));
    float gB = 1.f / (1.f + expf(-gtB));
    float qB0 = vB0*gB, qB1 = vB1*gB, qB2 = vB2*gB;
    // no barrier needed: B4's ch reads are fenced by the barrier above, and
    // B5's afeat reads don't touch ch.

    // B6: dtp3 (thread-local inputs)
    {
        ch[mA*256 + posA] = make_float4(sactA*evAx, sactA*evAy, sactA*evAz, sactA*esA);
        float dA = qA0*evAx + qA1*evAy + qA2*evAz;
        ch[mA*256 + posB] = make_float4(esA*qA0, esA*qA1, esA*qA2, dA);
        ch[mB*256 + posA] = make_float4(sactB*evBx, sactB*evBy, sactB*evBz, sactB*esB);
        float dB = qB0*evBx + qB1*evBy + qB2*evBz;
        ch[mB*256 + posB] = make_float4(esB*qB0, esB*qB1, esB*qB2, dB);
    }
    __syncthreads();

    // B7: Wval -> packed coalesced ebuf
    {
        const float bval_r = bval[o];
        float sA = bval_r, uA0 = 0.f, uA1 = 0.f, uA2 = 0.f;
        float sB = bval_r, uB0 = 0.f, uB1 = 0.f, uB2 = 0.f;
        #pragma unroll 4
        for (int i = 0; i < 32; ++i) {
            int ph = (i + rot2) & 31;
            float4 cA = ch[chA + ph];
            float4 cB = ch[chB + ph];
            float ws = Wval_s[i*16 + o];
            float wv = Wval_v[i*16 + o];
            sA += cA.w*ws; uA0 += cA.x*wv; uA1 += cA.y*wv; uA2 += cA.z*wv;
            sB += cB.w*ws; uB0 += cB.x*wv; uB1 += cB.y*wv; uB2 += cB.z*wv;
        }
        ebuf4[(size_t)eA*D_F + c] = make_float4(uA0, uA1, uA2, sA);
        ebuf4[(size_t)eB*D_F + c] = make_float4(uB0, uB1, uB2, sB);
    }
}

// ---------------------------------------------------------------------------
// k_finish: per-n softmax + attention-weighted sum + Wo linear + skip add
// ---------------------------------------------------------------------------
__global__ __launch_bounds__(128) void k_finish(
    const float4* __restrict__ ebuf4,
    float* __restrict__ attn_out,     // in: raw logits, out: probabilities
    const float* __restrict__ skip_s, const float* __restrict__ skip_v,
    const float* __restrict__ Wo_s, const float* __restrict__ Wo_v, const float* __restrict__ bo,
    float* __restrict__ out0, float* __restrict__ out1)
{
    const int n = blockIdx.x, t = threadIdx.x;
    __shared__ float sh_attn[H_N*K_E];
    __shared__ float4 sh_o[D_F];          // .xyz = outv_pre, .w = outs_pre
    if (t < H_N) {
        float lg[K_E];
        float mx = NEGMAX;
        #pragma unroll 4
        for (int k = 0; k < K_E; ++k) {
            lg[k] = attn_out[t*(N_Q*K_E) + n*K_E + k];
            mx = fmaxf(mx, lg[k]);
        }
        float sum = 0.f;
        #pragma unroll 4
        for (int k = 0; k < K_E; ++k) { float p = expf(lg[k]-mx); lg[k] = p; sum += p; }
        float rinv = 1.f/sum;
        #pragma unroll 4
        for (int k = 0; k < K_E; ++k) {
            float a = lg[k]*rinv;
            sh_attn[t*K_E + k] = a;
            attn_out[t*(N_Q*K_E) + n*K_E + k] = a;
        }
    }
    __syncthreads();
    const int h = t >> 4;
    float accs = 0.f, a0 = 0.f, a1 = 0.f, a2 = 0.f;
    #pragma unroll 4
    for (int k = 0; k < K_E; ++k) {
        float a = sh_attn[h*K_E + k];
        float4 eb = ebuf4[(size_t)(n*K_E + k)*D_F + t];
        accs += a*eb.w;
        a0 += a*eb.x; a1 += a*eb.y; a2 += a*eb.z;
    }
    sh_o[t] = make_float4(a0, a1, a2, accs);
    __syncthreads();
    float acc = bo[t], o0 = 0.f, o1 = 0.f, o2 = 0.f;
    #pragma unroll 4
    for (int i = 0; i < D_F; ++i) {
        float4 pv = sh_o[i];
        float ws = Wo_s[i*D_F + t]; acc += pv.w*ws;
        float wv = Wo_v[i*D_F + t];
        o0 += pv.x*wv; o1 += pv.y*wv; o2 += pv.z*wv;
    }
    out0[n*D_F + t] = acc + skip_s[n*D_F + t];
    out1[(n*D_F + t)*3 + 0] = o0 + skip_v[(n*D_F + t)*3 + 0];
    out1[(n*D_F + t)*3 + 1] = o1 + skip_v[(n*D_F + t)*3 + 1];
    out1[(n*D_F + t)*3 + 2] = o2 + skip_v[(n*D_F + t)*3 + 2];
}

// ---------------------------------------------------------------------------
extern "C" void kernel_launch(void* const* d_in, const int* in_sizes, int n_in,
                              void* d_out, int out_size, void* d_ws, size_t ws_size,
                              hipStream_t stream)
{
    (void)in_sizes; (void)n_in; (void)out_size; (void)ws_size;

    const float* query_s = (const float*)d_in[0];
    const float* query_v = (const float*)d_in[1];
    const float* key_s   = (const float*)d_in[2];
    const float* key_v   = (const float*)d_in[3];
    const float* eis     = (const float*)d_in[4];
    const float* eiv     = (const float*)d_in[5];
    const float* eemb    = (const float*)d_in[6];
    const int*   mask    = (const int*)d_in[7];
    const int*   knn     = (const int*)d_in[8];
    const float* Wq_s    = (const float*)d_in[9];
    const float* Wq_v    = (const float*)d_in[10];
    const float* bq      = (const float*)d_in[11];
    const float* Wk_s    = (const float*)d_in[12];
    const float* Wk_v    = (const float*)d_in[13];
    const float* bk      = (const float*)d_in[14];
    const float* Wqk_s   = (const float*)d_in[15];
    const float* Wqk_v   = (const float*)d_in[16];
    const float* bqk     = (const float*)d_in[17];
    const float* Wdtp    = (const float*)d_in[18];
    const float* bdtp    = (const float*)d_in[19];
    const float* Wagv_s  = (const float*)d_in[20];
    const float* bagv    = (const float*)d_in[21];
    const float* Wagv_v  = (const float*)d_in[22];
    const float* Wattn   = (const float*)d_in[23];
    const float* Wval_s  = (const float*)d_in[24];
    const float* Wval_v  = (const float*)d_in[25];
    const float* bval    = (const float*)d_in[26];
    const float* Wo_s    = (const float*)d_in[27];
    const float* Wo_v    = (const float*)d_in[28];
    const float* bo      = (const float*)d_in[29];
    const float* ln_gs   = (const float*)d_in[30];
    const float* ln_bs   = (const float*)d_in[31];
    const float* ln_gv   = (const float*)d_in[32];
    const float* lna_g   = (const float*)d_in[33];
    const float* lna_b   = (const float*)d_in[34];

    float* out      = (float*)d_out;
    float* out_s    = out;
    float* out_v    = out + N_Q*D_F;
    float* out_attn = out + N_Q*D_F*4;

    float* ws = (float*)d_ws;
    float4* q4     = (float4*)ws;                      // N*128 f4 = 4 MB
    float4* k4     = q4 + N_Q*D_F;                     // 4 MB
    float*  skip_s = (float*)(k4 + N_Q*D_F);           // 1 MB
    float*  skip_v = skip_s + N_Q*D_F;                 // 3 MB
    float4* ebuf4  = (float4*)(skip_v + N_Q*D_F*3);    // N*K*128 f4 = 134 MB

    hipLaunchKernelGGL(k_qk, dim3(2*N_Q), dim3(D_F), 0, stream,
                       query_s, query_v, key_s, key_v,
                       Wq_s, Wq_v, bq, Wk_s, Wk_v, bk,
                       ln_gs, ln_bs, ln_gv,
                       q4, k4, skip_s, skip_v);
    hipLaunchKernelGGL(k_edge_bulk, dim3(N_Q*K_E/EPB), dim3(512), 0, stream,
                       q4, k4, eis, eiv, eemb, mask, knn,
                       Wqk_s, Wqk_v, bqk, Wdtp, bdtp,
                       Wagv_s, bagv, Wagv_v, Wattn, lna_g, lna_b,
                       Wval_s, Wval_v, bval,
                       ebuf4, out_attn);
    hipLaunchKernelGGL(k_finish, dim3(N_Q), dim3(D_F), 0, stream,
                       ebuf4, out_attn, skip_s, skip_v, Wo_s, Wo_v, bo,
                       out_s, out_v);
}